// Round 6
// baseline (269.346 us; speedup 1.0000x reference)
//
#include <hip/hip_runtime.h>

#define HW 9216
#define WIDTH 96
#define NCLS 20
#define NOUT 25   // 1 obj + 20 cls + 4 reg
#define CAP 1024
#define NW 16     // CAP/64 mask words per row

// ws layout:
//   [0,256)            cnt[64] u32 (zeroed by gemm_stage1 block 0)
//   [256, 256+160K)    keys[NCLS][CAP] u64
//   [164096, +7.37MB)  partial[8][NOUT][HW] f32
#define WS_KEYS   256
#define WS_PART   164096

// ---------------------------------------------------------------------------
// K1a: GEMM stage 1 (verified bit-exact in R5). Block = 256 positions, one
// 64-channel chunk g = blockIdx&7; channel index wave-uniform -> scalar-pipe
// weight loads. unroll 16 -> ~32 feature loads in flight (latency hiding at
// ~1 wave/SIMD). Block 0 also zeroes the per-class counters (replaces the
// memset dispatch; safe: cnt first read in stage2, stream-ordered).
// ---------------------------------------------------------------------------
__global__ __launch_bounds__(256) void gemm_stage1(
    const float* __restrict__ cls_feat, const float* __restrict__ reg_feat,
    const float* __restrict__ obj_w, const float* __restrict__ cls_w,
    const float* __restrict__ reg_w, float* __restrict__ partial,
    unsigned* __restrict__ cnt)
{
    if (blockIdx.x == 0 && threadIdx.x < 64) cnt[threadIdx.x] = 0u;

    const int g   = blockIdx.x & 7;
    const int pos = (blockIdx.x >> 3) * 256 + threadIdx.x;
    const int cb  = g * 64;

    float acc[NOUT];
#pragma unroll
    for (int o = 0; o < NOUT; ++o) acc[o] = 0.f;

    const float* cf = cls_feat + (size_t)cb * HW + pos;
    const float* rf = reg_feat + (size_t)cb * HW + pos;

#pragma unroll 16
    for (int k = 0; k < 64; ++k) {
        const int c = cb + k;                 // uniform -> s_load weights
        float f = cf[(size_t)k * HW];
        float h = rf[(size_t)k * HW];
        acc[0] += f * obj_w[c];
#pragma unroll
        for (int j = 0; j < 20; ++j) acc[1 + j] += f * cls_w[j * 512 + c];
#pragma unroll
        for (int j = 0; j < 4; ++j)  acc[21 + j] += h * reg_w[j * 512 + c];
    }

    float* pg = partial + (size_t)g * NOUT * HW + pos;
#pragma unroll
    for (int o = 0; o < NOUT; ++o) pg[(size_t)o * HW] = acc[o];
}

// ---------------------------------------------------------------------------
// K1b: left-fold chunk partials g=0..7 + decode epilogue (verified R5).
// ---------------------------------------------------------------------------
__global__ __launch_bounds__(256) void decode_stage2(
    const float* __restrict__ partial,
    const float* __restrict__ obj_b, const float* __restrict__ cls_b,
    const float* __restrict__ reg_b,
    float* __restrict__ out, unsigned* __restrict__ cnt,
    unsigned long long* __restrict__ keys)
{
    const int pp = blockIdx.x * 256 + threadIdx.x;

    float d[NOUT];
#pragma unroll
    for (int o = 0; o < NOUT; ++o) {
        float s = 0.f;
#pragma unroll
        for (int g = 0; g < 8; ++g)
            s += partial[((size_t)g * NOUT + o) * HW + pp];
        d[o] = s;
    }

    float obj  = d[0] + obj_b[0];
    float best = d[1] + cls_b[0];
    int   bk   = 0;
#pragma unroll
    for (int k = 1; k < NCLS; ++k) {
        float v = d[1 + k] + cls_b[k];
        if (v > best) { best = v; bk = k; }   // strict > == first-max
    }
    float sobj  = 1.f / (1.f + expf(-obj));
    float scls  = 1.f / (1.f + expf(-best));
    float score = sobj * scls;

    float r0 = d[21] + reg_b[0], r1 = d[22] + reg_b[1];
    float r2 = d[23] + reg_b[2], r3 = d[24] + reg_b[3];
    float gx = (float)(pp % WIDTH), gy = (float)(pp / WIDTH);
    float cx = (1.f / (1.f + expf(-r0)) + gx) * 32.f;
    float cy = (1.f / (1.f + expf(-r1)) + gy) * 32.f;
    float bw = expf(r2) * 32.f;
    float bh = expf(r3) * 32.f;
    float hx = 0.5f * bw, hy = 0.5f * bh;

    ((float4*)out)[pp] = make_float4(cx - hx, cy - hy, cx + hx, cy + hy);
    out[HW * 4 + pp] = score;
    out[HW * 5 + pp] = (float)bk;
    out[HW * 6 + pp] = 0.f;

    if (score >= 0.01f) {
        unsigned slot = atomicAdd(&cnt[bk], 1u);
        if (slot < CAP) {
            unsigned sb = __float_as_uint(score) ^ 0xffffffffu;
            keys[bk * CAP + slot] = ((unsigned long long)sb << 32) | (unsigned)pp;
        }
    }
}

// ---------------------------------------------------------------------------
// K2: fused NMS — register bitonic sort + LDS mask build + wave-0 sweep.
// One block per class, 1024 threads, 148 KB LDS. All three phases are the
// verified (absmax 0) algorithms; only data placement changed (mask: HBM->LDS,
// sorted keys: never leave registers/LDS).
// ---------------------------------------------------------------------------
__device__ __forceinline__ unsigned long long shflxor64(unsigned long long v, int msk) {
    unsigned lo = __shfl_xor((unsigned)v, msk, 64);
    unsigned hi = __shfl_xor((unsigned)(v >> 32), msk, 64);
    return ((unsigned long long)hi << 32) | lo;
}
__device__ __forceinline__ unsigned long long uread64(unsigned long long v, int srclane) {
    unsigned lo = __builtin_amdgcn_readlane((unsigned)v, srclane);
    unsigned hi = __builtin_amdgcn_readlane((unsigned)(v >> 32), srclane);
    return ((unsigned long long)hi << 32) | lo;
}

__global__ __launch_bounds__(1024) void nms_fused(
    const unsigned* __restrict__ cnt, const unsigned long long* __restrict__ keys,
    const float* __restrict__ bboxes, float* __restrict__ keep)
{
    __shared__ unsigned long long smask[CAP * NW];   // 128 KB; [0,CAP) doubles as sort buffer
    __shared__ float4  box[CAP];                     // 16 KB
    __shared__ unsigned lidx[CAP];                   // 4 KB

    const int c = blockIdx.x, tid = threadIdx.x;
    const int wave = tid >> 6, lane = tid & 63;
    int m = (int)cnt[c]; if (m > CAP) m = CAP;
    const int nw = (m + 63) >> 6;

    // ---- phase 1: register bitonic sort (verbatim R5 logic) ----
    unsigned long long v = (tid < m) ? keys[c * CAP + tid] : 0xFFFFFFFFFFFFFFFFull;
    for (int k = 2; k <= CAP; k <<= 1) {
        for (int j = k >> 1; j > 0; j >>= 1) {
            unsigned long long u;
            if (j >= 64) {
                __syncthreads();
                smask[tid] = v;
                __syncthreads();
                u = smask[tid ^ j];
            } else {
                u = shflxor64(v, j);
            }
            const bool takeSmall = (((tid & k) == 0) == ((tid & j) == 0));
            const bool less = v < u;
            v = (takeSmall == less) ? v : u;
        }
    }
    __syncthreads();   // all sort-buffer reads retired before mask reuse

    // ---- phase 2: zero mask, gather boxes by sorted order ----
    for (int i = tid; i < CAP * NW; i += 1024) smask[i] = 0ull;
    if (tid < m) {
        unsigned idx = (unsigned)(v & 0xffffffffu);
        lidx[tid] = idx;
        box[tid]  = ((const float4*)bboxes)[idx];
    } else {
        box[tid] = make_float4(0.f, 0.f, 0.f, 0.f);
    }
    __syncthreads();

    // ---- phase 3: build suppression words into LDS ----
    // j-columns cached in registers (static indices via unrolled w + break).
    float jx1[16], jy1[16], jx2[16], jy2[16], jar[16];
#pragma unroll
    for (int w = 0; w < 16; ++w) {
        float4 b = box[(w << 6) + lane];
        jx1[w] = b.x; jy1[w] = b.y; jx2[w] = b.z; jy2[w] = b.w;
        jar[w] = (b.z - b.x) * (b.w - b.y);
    }
    for (int r = wave; r < m; r += 16) {
        const float4 bi = box[r];                       // uniform per wave
        const float ai = (bi.z - bi.x) * (bi.w - bi.y);
#pragma unroll
        for (int w = 0; w < 16; ++w) {
            if (w >= nw) break;                         // uniform
            const int j = (w << 6) + lane;
            float iw = fminf(bi.z, jx2[w]) - fmaxf(bi.x, jx1[w]);
            float ih = fminf(bi.w, jy2[w]) - fmaxf(bi.y, jy1[w]);
            iw = fmaxf(iw, 1e-10f);
            ih = fmaxf(ih, 1e-10f);
            const float inter = iw * ih;
            const float iou = inter / (ai + jar[w] - inter);
            unsigned long long word = __ballot((j < m) && (iou > 0.5f));
            if (lane == 0) smask[r * NW + w] = word;
        }
    }
    __syncthreads();

    // ---- phase 4: greedy sweep, wave 0 only (verified cascade) ----
    if (wave == 0) {
        const int wsel = lane & 15;
        const int rof  = lane >> 4;
        unsigned long long remw = 0;
        for (int w = 0; w < nw; ++w) {
            const int i0 = w << 6;
            const int nb = min(64, m - i0);

            unsigned long long myrow =
                (lane < nb) ? smask[(i0 + lane) * NW + w] : 0ull;

            unsigned long long rw[16];
#pragma unroll
            for (int j = 0; j < 16; ++j)
                rw[j] = smask[(i0 + rof + (j << 2)) * NW + wsel]; // zeroed pad

            unsigned long long cur  = uread64(remw, w);
            unsigned long long kept = 0;
#pragma unroll
            for (int b = 0; b < 64; ++b) {
                unsigned long long x = uread64(myrow, b);
                unsigned long long alive = ((cur >> b) & 1ull) ^ 1ull;
                kept |= alive << b;
                cur |= x & (0ull - alive);
            }
            if (nb < 64) kept &= (1ull << nb) - 1ull;

            if (lane < nb && ((kept >> lane) & 1ull))
                keep[lidx[i0 + lane]] = 1.0f;

            unsigned long long part = 0;
#pragma unroll
            for (int j = 0; j < 16; ++j) {
                const int b = rof + (j << 2);
                part |= rw[j] & (0ull - ((kept >> b) & 1ull));
            }
            part |= shflxor64(part, 16);
            part |= shflxor64(part, 32);
            if (lane < NW) remw |= part;
        }
    }
}

// ---------------------------------------------------------------------------
extern "C" void kernel_launch(void* const* d_in, const int* in_sizes, int n_in,
                              void* d_out, int out_size, void* d_ws, size_t ws_size,
                              hipStream_t stream)
{
    const float* cls_feat = (const float*)d_in[0];
    const float* reg_feat = (const float*)d_in[1];
    const float* obj_w    = (const float*)d_in[2];
    const float* obj_b    = (const float*)d_in[3];
    const float* cls_w    = (const float*)d_in[4];
    const float* cls_b    = (const float*)d_in[5];
    const float* reg_w    = (const float*)d_in[6];
    const float* reg_b    = (const float*)d_in[7];

    float* out = (float*)d_out;
    unsigned* cnt            = (unsigned*)d_ws;
    unsigned long long* keys = (unsigned long long*)((char*)d_ws + WS_KEYS);
    float* partial           = (float*)((char*)d_ws + WS_PART);

    gemm_stage1<<<288, 256, 0, stream>>>(cls_feat, reg_feat,
                                         obj_w, cls_w, reg_w, partial, cnt);
    decode_stage2<<<HW / 256, 256, 0, stream>>>(partial, obj_b, cls_b, reg_b,
                                                out, cnt, keys);
    nms_fused<<<NCLS, 1024, 0, stream>>>(cnt, keys, out, out + HW * 6);
}

// Round 8
// 190.896 us; speedup vs baseline: 1.4110x; 1.4110x over previous
//
#include <hip/hip_runtime.h>

#define HW 9216
#define WIDTH 96
#define NCLS 20
#define NOUT 25   // 1 obj + 20 cls + 4 reg
#define CAP 1024
#define NW 16     // CAP/64 mask words per row

// ws layout (no overlays):
//   [0,256)              cnt[64] u32 (zeroed by gemm_stage1 block 0)
//   [256, +160K)         keys[NCLS][CAP] u64
//   [164096, +7.37MB)    partial[8][NOUT][HW] f32
//   [7536896, +2.56MB)   mask[NCLS][CAP][NW] u64
#define WS_KEYS   256
#define WS_PART   164096
#define WS_MASK   7536896

// ---------------------------------------------------------------------------
// K1a: GEMM stage 1. Block = 256 positions x one 64-channel chunk (g =
// blockIdx&7). Weights staged in 6.5KB LDS; k-loop reads are BLOCK-UNIFORM
// float4 -> bank-conflict-free broadcast. Per-k FMA sequence identical to
// the verified R5/R6 stage1 (same addends, same order -> bit-exact).
// ---------------------------------------------------------------------------
__global__ __launch_bounds__(256) void gemm_stage1(
    const float* __restrict__ cls_feat, const float* __restrict__ reg_feat,
    const float* __restrict__ obj_w, const float* __restrict__ cls_w,
    const float* __restrict__ reg_w, float* __restrict__ partial,
    unsigned* __restrict__ cnt)
{
    if (blockIdx.x == 0 && threadIdx.x < 64) cnt[threadIdx.x] = 0u;

    __shared__ float wlds[64 * 28];   // [k][o], 28-stride for float4 rows
    const int g   = blockIdx.x & 7;
    const int pos = (blockIdx.x >> 3) * 256 + threadIdx.x;
    const int cb  = g * 64;

    // stage 64ch x 25 outs, o-major (k fastest -> coalesced global reads)
    for (int i = threadIdx.x; i < 64 * 25; i += 256) {
        const int o = i >> 6, k = i & 63;
        float v;
        if (o == 0)        v = obj_w[cb + k];
        else if (o < 21)   v = cls_w[(o - 1) * 512 + cb + k];
        else               v = reg_w[(o - 21) * 512 + cb + k];
        wlds[k * 28 + o] = v;
    }
    __syncthreads();

    float acc[NOUT];
#pragma unroll
    for (int o = 0; o < NOUT; ++o) acc[o] = 0.f;

    const float* cf = cls_feat + (size_t)cb * HW + pos;
    const float* rf = reg_feat + (size_t)cb * HW + pos;

#pragma unroll 8
    for (int k = 0; k < 64; ++k) {
        float f = cf[(size_t)k * HW];
        float h = rf[(size_t)k * HW];
        const float4* w = (const float4*)(wlds + k * 28);  // uniform -> broadcast
        float4 w0 = w[0], w1 = w[1], w2 = w[2], w3 = w[3], w4v = w[4], w5 = w[5], w6 = w[6];
        acc[0]  += f * w0.x;  acc[1]  += f * w0.y;  acc[2]  += f * w0.z;  acc[3]  += f * w0.w;
        acc[4]  += f * w1.x;  acc[5]  += f * w1.y;  acc[6]  += f * w1.z;  acc[7]  += f * w1.w;
        acc[8]  += f * w2.x;  acc[9]  += f * w2.y;  acc[10] += f * w2.z;  acc[11] += f * w2.w;
        acc[12] += f * w3.x;  acc[13] += f * w3.y;  acc[14] += f * w3.z;  acc[15] += f * w3.w;
        acc[16] += f * w4v.x; acc[17] += f * w4v.y; acc[18] += f * w4v.z; acc[19] += f * w4v.w;
        acc[20] += f * w5.x;
        acc[21] += h * w5.y;  acc[22] += h * w5.z;  acc[23] += h * w5.w;  acc[24] += h * w6.x;
    }

    float* pg = partial + (size_t)g * NOUT * HW + pos;
#pragma unroll
    for (int o = 0; o < NOUT; ++o) pg[(size_t)o * HW] = acc[o];
}

// ---------------------------------------------------------------------------
// K1b: left-fold chunk partials g=0..7 + decode epilogue (verified R5/R6).
// launch_bounds(256,1) uncaps VGPRs -> ~all 200 partial loads in flight.
// ---------------------------------------------------------------------------
__global__ __launch_bounds__(256, 1) void decode_stage2(
    const float* __restrict__ partial,
    const float* __restrict__ obj_b, const float* __restrict__ cls_b,
    const float* __restrict__ reg_b,
    float* __restrict__ out, unsigned* __restrict__ cnt,
    unsigned long long* __restrict__ keys)
{
    const int pp = blockIdx.x * 256 + threadIdx.x;

    float d[NOUT];
#pragma unroll
    for (int o = 0; o < NOUT; ++o) {
        float s = 0.f;
#pragma unroll
        for (int g = 0; g < 8; ++g)
            s += partial[((size_t)g * NOUT + o) * HW + pp];
        d[o] = s;
    }

    float obj  = d[0] + obj_b[0];
    float best = d[1] + cls_b[0];
    int   bk   = 0;
#pragma unroll
    for (int k = 1; k < NCLS; ++k) {
        float v = d[1 + k] + cls_b[k];
        if (v > best) { best = v; bk = k; }   // strict > == first-max
    }
    float sobj  = 1.f / (1.f + expf(-obj));
    float scls  = 1.f / (1.f + expf(-best));
    float score = sobj * scls;

    float r0 = d[21] + reg_b[0], r1 = d[22] + reg_b[1];
    float r2 = d[23] + reg_b[2], r3 = d[24] + reg_b[3];
    float gx = (float)(pp % WIDTH), gy = (float)(pp / WIDTH);
    float cx = (1.f / (1.f + expf(-r0)) + gx) * 32.f;
    float cy = (1.f / (1.f + expf(-r1)) + gy) * 32.f;
    float bw = expf(r2) * 32.f;
    float bh = expf(r3) * 32.f;
    float hx = 0.5f * bw, hy = 0.5f * bh;

    ((float4*)out)[pp] = make_float4(cx - hx, cy - hy, cx + hx, cy + hy);
    out[HW * 4 + pp] = score;
    out[HW * 5 + pp] = (float)bk;
    out[HW * 6 + pp] = 0.f;

    if (score >= 0.01f) {
        unsigned slot = atomicAdd(&cnt[bk], 1u);
        if (slot < CAP) {
            unsigned sb = __float_as_uint(score) ^ 0xffffffffu;
            keys[bk * CAP + slot] = ((unsigned long long)sb << 32) | (unsigned)pp;
        }
    }
}

// ---------------------------------------------------------------------------
// K2: register bitonic sort (verified R5). 1024 thr x 1 elem; j<64 stages in
// shfl_xor, j>=64 through LDS.
// ---------------------------------------------------------------------------
__device__ __forceinline__ unsigned long long shflxor64(unsigned long long v, int msk) {
    unsigned lo = __shfl_xor((unsigned)v, msk, 64);
    unsigned hi = __shfl_xor((unsigned)(v >> 32), msk, 64);
    return ((unsigned long long)hi << 32) | lo;
}

__global__ __launch_bounds__(1024) void sort_kernel(
    const unsigned* __restrict__ cnt, unsigned long long* __restrict__ keys)
{
    __shared__ unsigned long long a[CAP];
    const int c = blockIdx.x, i = threadIdx.x;
    unsigned m = cnt[c]; if (m > CAP) m = CAP;

    unsigned long long v = (i < (int)m) ? keys[c * CAP + i]
                                        : 0xFFFFFFFFFFFFFFFFull;

    for (int k = 2; k <= CAP; k <<= 1) {
        for (int j = k >> 1; j > 0; j >>= 1) {
            unsigned long long u;
            if (j >= 64) {
                __syncthreads();
                a[i] = v;
                __syncthreads();
                u = a[i ^ j];
            } else {
                u = shflxor64(v, j);
            }
            const bool takeSmall = (((i & k) == 0) == ((i & j) == 0));
            const bool less = v < u;
            v = (takeSmall == less) ? v : u;
        }
    }
    if (i < (int)m) keys[c * CAP + i] = v;
}

// ---------------------------------------------------------------------------
// K3a: parallel mask build (verified R3-R5). 320 blocks -> whole-chip.
// ---------------------------------------------------------------------------
__global__ __launch_bounds__(1024) void build_kernel(
    const unsigned* __restrict__ cnt, const unsigned long long* __restrict__ keys,
    const float* __restrict__ bboxes, unsigned long long* __restrict__ mask)
{
    __shared__ float4 box[CAP];
    const int c = blockIdx.x >> 4, tile = blockIdx.x & 15;
    const int tid = threadIdx.x, wave = tid >> 6, lane = tid & 63;
    int m = (int)cnt[c]; if (m > CAP) m = CAP;
    const int rbase = tile << 6;
    if (rbase >= m) return;                      // uniform; before any barrier

    if (tid < m) {
        unsigned idx = (unsigned)(keys[c * CAP + tid] & 0xffffffffu);
        box[tid] = ((const float4*)bboxes)[idx];
    } else {
        box[tid] = make_float4(0.f, 0.f, 0.f, 0.f);
    }
    __syncthreads();

    unsigned long long* mrow = mask + (size_t)c * CAP * NW;
#pragma unroll 4
    for (int j = 0; j < 64; ++j) {
        const int row = rbase + (wave << 2) + (j >> 4);   // uniform per wave
        const int w   = j & 15;
        const float4 bi = box[row];
        const float4 bj = box[(w << 6) + lane];
        const float ai = (bi.z - bi.x) * (bi.w - bi.y);
        const float aj = (bj.z - bj.x) * (bj.w - bj.y);
        float iw = fminf(bi.z, bj.z) - fmaxf(bi.x, bj.x);
        float ih = fminf(bi.w, bj.w) - fmaxf(bi.y, bj.y);
        iw = fmaxf(iw, 1e-10f);
        ih = fmaxf(ih, 1e-10f);
        const float inter = iw * ih;
        const float iou = inter / (ai + aj - inter);
        unsigned long long word =
            __ballot((row < m) && (((w << 6) + lane) < m) && (iou > 0.5f));
        if (lane == 0) mrow[row * NW + w] = word;
    }
}

// ---------------------------------------------------------------------------
// K3b: greedy sweep, software-pipelined: w+1's 18 loads issue BEFORE w's
// cascade; register rotation puts the vmcnt wait after ~600cy of cascade.
// Cascade recurrence identical to verified R4-R5 sweep.
// ---------------------------------------------------------------------------
__device__ __forceinline__ unsigned long long uread64(unsigned long long v, int srclane) {
    unsigned lo = __builtin_amdgcn_readlane((unsigned)v, srclane);
    unsigned hi = __builtin_amdgcn_readlane((unsigned)(v >> 32), srclane);
    return ((unsigned long long)hi << 32) | lo;
}

__global__ __launch_bounds__(64) void sweep_kernel(
    const unsigned* __restrict__ cnt, const unsigned long long* __restrict__ keys,
    const unsigned long long* __restrict__ mask, float* __restrict__ keep)
{
    const int c = blockIdx.x, lane = threadIdx.x;
    int m = (int)cnt[c]; if (m > CAP) m = CAP;
    const int nw = (m + 63) >> 6;
    if (nw == 0) return;
    const unsigned long long* mrow = mask + (size_t)c * CAP * NW;

    const int wsel = lane & 15;
    const int rof  = lane >> 4;

    // prologue: loads for w = 0
    unsigned long long keyA =
        (lane < m) ? keys[c * CAP + lane] : 0ull;
    unsigned long long rowA =
        (lane < m) ? mrow[(size_t)lane * NW + 0] : 0ull;
    unsigned long long rwA[16];
#pragma unroll
    for (int j = 0; j < 16; ++j) {
        const int r = rof + (j << 2);
        rwA[j] = (r < m && wsel < nw) ? mrow[(size_t)r * NW + wsel] : 0ull;
    }

    unsigned long long remw = 0;     // lane l holds rem word l (l < NW)
    for (int w = 0; w < nw; ++w) {
        const int i0 = w << 6;
        const int nb = min(64, m - i0);

        // stage w+1 (exec-masked off when !more; consumed next iteration)
        const bool more = (w + 1 < nw);
        const int  i1   = (w + 1) << 6;
        unsigned long long keyB =
            (more && i1 + lane < m) ? keys[c * CAP + i1 + lane] : 0ull;
        unsigned long long rowB =
            (more && i1 + lane < m) ? mrow[(size_t)(i1 + lane) * NW + (w + 1)] : 0ull;
        unsigned long long rwB[16];
#pragma unroll
        for (int j = 0; j < 16; ++j) {
            const int r = i1 + rof + (j << 2);
            rwB[j] = (more && r < m && wsel < nw)
                         ? mrow[(size_t)r * NW + wsel] : 0ull;
        }

        // serial cascade (verified recurrence)
        unsigned long long cur  = uread64(remw, w);
        unsigned long long kept = 0;
#pragma unroll
        for (int b = 0; b < 64; ++b) {
            unsigned long long x = uread64(rowA, b);
            unsigned long long alive = ((cur >> b) & 1ull) ^ 1ull;
            kept |= alive << b;
            cur |= x & (0ull - alive);
        }
        if (nb < 64) kept &= (1ull << nb) - 1ull;

        if (lane < nb && ((kept >> lane) & 1ull))
            keep[(unsigned)(keyA & 0xffffffffu)] = 1.0f;

        // branch-free OR of kept rows into rem
        unsigned long long part = 0;
#pragma unroll
        for (int j = 0; j < 16; ++j) {
            const int b = rof + (j << 2);
            part |= rwA[j] & (0ull - ((kept >> b) & 1ull));
        }
        part |= shflxor64(part, 16);
        part |= shflxor64(part, 32);
        if (lane < NW) remw |= part;

        // rotate pipeline registers
        keyA = keyB;
        rowA = rowB;
#pragma unroll
        for (int j = 0; j < 16; ++j) rwA[j] = rwB[j];
    }
}

// ---------------------------------------------------------------------------
extern "C" void kernel_launch(void* const* d_in, const int* in_sizes, int n_in,
                              void* d_out, int out_size, void* d_ws, size_t ws_size,
                              hipStream_t stream)
{
    const float* cls_feat = (const float*)d_in[0];
    const float* reg_feat = (const float*)d_in[1];
    const float* obj_w    = (const float*)d_in[2];
    const float* obj_b    = (const float*)d_in[3];
    const float* cls_w    = (const float*)d_in[4];
    const float* cls_b    = (const float*)d_in[5];
    const float* reg_w    = (const float*)d_in[6];
    const float* reg_b    = (const float*)d_in[7];

    float* out = (float*)d_out;
    unsigned* cnt            = (unsigned*)d_ws;
    unsigned long long* keys = (unsigned long long*)((char*)d_ws + WS_KEYS);
    float* partial           = (float*)((char*)d_ws + WS_PART);
    unsigned long long* mask = (unsigned long long*)((char*)d_ws + WS_MASK);

    gemm_stage1<<<288, 256, 0, stream>>>(cls_feat, reg_feat,
                                         obj_w, cls_w, reg_w, partial, cnt);
    decode_stage2<<<HW / 256, 256, 0, stream>>>(partial, obj_b, cls_b, reg_b,
                                                out, cnt, keys);
    sort_kernel<<<NCLS, 1024, 0, stream>>>(cnt, keys);
    build_kernel<<<NCLS * 16, 1024, 0, stream>>>(cnt, keys, out, mask);
    sweep_kernel<<<NCLS, 64, 0, stream>>>(cnt, keys, mask, out + HW * 6);
}

// Round 10
// 188.971 us; speedup vs baseline: 1.4253x; 1.0102x over previous
//
#include <hip/hip_runtime.h>

#define HW 9216
#define WIDTH 96
#define NCLS 20
#define NOUT 25   // 1 obj + 20 cls + 4 reg
#define CAP 1024
#define NW 16     // CAP/64 mask words per row

// ws layout:
//   [0,256)              cnt[64] u32 (zeroed by gemm_stage1 block 0)
//   [256, +160K)         keys[NCLS][CAP] u64      (atomic insertion order)
//   [164096, +7.37MB)    partial[8][NOUT][HW] f32
//   [7536896, +2.56MB)   mask[NCLS][CAP][NW] u64
//   [10158336, +160K)    keys2[NCLS][CAP] u64     (rank-sorted)
#define WS_KEYS   256
#define WS_PART   164096
#define WS_MASK   7536896
#define WS_KEY2   10158336

// ---------------------------------------------------------------------------
// K1a: GEMM stage 1 (verified R8). Block = 256 positions x one 64-ch chunk;
// weights staged in 6.5KB LDS, block-uniform float4 broadcast reads. Per-k
// FMA sequence identical to the verified monolithic kernel -> bit-exact.
// ---------------------------------------------------------------------------
__global__ __launch_bounds__(256) void gemm_stage1(
    const float* __restrict__ cls_feat, const float* __restrict__ reg_feat,
    const float* __restrict__ obj_w, const float* __restrict__ cls_w,
    const float* __restrict__ reg_w, float* __restrict__ partial,
    unsigned* __restrict__ cnt)
{
    if (blockIdx.x == 0 && threadIdx.x < 64) cnt[threadIdx.x] = 0u;

    __shared__ float wlds[64 * 28];   // [k][o], 28-stride for float4 rows
    const int g   = blockIdx.x & 7;
    const int pos = (blockIdx.x >> 3) * 256 + threadIdx.x;
    const int cb  = g * 64;

    for (int i = threadIdx.x; i < 64 * 25; i += 256) {
        const int o = i >> 6, k = i & 63;
        float v;
        if (o == 0)        v = obj_w[cb + k];
        else if (o < 21)   v = cls_w[(o - 1) * 512 + cb + k];
        else               v = reg_w[(o - 21) * 512 + cb + k];
        wlds[k * 28 + o] = v;
    }
    __syncthreads();

    float acc[NOUT];
#pragma unroll
    for (int o = 0; o < NOUT; ++o) acc[o] = 0.f;

    const float* cf = cls_feat + (size_t)cb * HW + pos;
    const float* rf = reg_feat + (size_t)cb * HW + pos;

#pragma unroll 8
    for (int k = 0; k < 64; ++k) {
        float f = cf[(size_t)k * HW];
        float h = rf[(size_t)k * HW];
        const float4* w = (const float4*)(wlds + k * 28);  // uniform -> broadcast
        float4 w0 = w[0], w1 = w[1], w2 = w[2], w3 = w[3], w4v = w[4], w5 = w[5], w6 = w[6];
        acc[0]  += f * w0.x;  acc[1]  += f * w0.y;  acc[2]  += f * w0.z;  acc[3]  += f * w0.w;
        acc[4]  += f * w1.x;  acc[5]  += f * w1.y;  acc[6]  += f * w1.z;  acc[7]  += f * w1.w;
        acc[8]  += f * w2.x;  acc[9]  += f * w2.y;  acc[10] += f * w2.z;  acc[11] += f * w2.w;
        acc[12] += f * w3.x;  acc[13] += f * w3.y;  acc[14] += f * w3.z;  acc[15] += f * w3.w;
        acc[16] += f * w4v.x; acc[17] += f * w4v.y; acc[18] += f * w4v.z; acc[19] += f * w4v.w;
        acc[20] += f * w5.x;
        acc[21] += h * w5.y;  acc[22] += h * w5.z;  acc[23] += h * w5.w;  acc[24] += h * w6.x;
    }

    float* pg = partial + (size_t)g * NOUT * HW + pos;
#pragma unroll
    for (int o = 0; o < NOUT; ++o) pg[(size_t)o * HW] = acc[o];
}

// ---------------------------------------------------------------------------
// K1b: left-fold chunk partials g=0..7 + decode epilogue (verified R8).
// ---------------------------------------------------------------------------
__global__ __launch_bounds__(256, 1) void decode_stage2(
    const float* __restrict__ partial,
    const float* __restrict__ obj_b, const float* __restrict__ cls_b,
    const float* __restrict__ reg_b,
    float* __restrict__ out, unsigned* __restrict__ cnt,
    unsigned long long* __restrict__ keys)
{
    const int pp = blockIdx.x * 256 + threadIdx.x;

    float d[NOUT];
#pragma unroll
    for (int o = 0; o < NOUT; ++o) {
        float s = 0.f;
#pragma unroll
        for (int g = 0; g < 8; ++g)
            s += partial[((size_t)g * NOUT + o) * HW + pp];
        d[o] = s;
    }

    float obj  = d[0] + obj_b[0];
    float best = d[1] + cls_b[0];
    int   bk   = 0;
#pragma unroll
    for (int k = 1; k < NCLS; ++k) {
        float v = d[1 + k] + cls_b[k];
        if (v > best) { best = v; bk = k; }   // strict > == first-max
    }
    float sobj  = 1.f / (1.f + expf(-obj));
    float scls  = 1.f / (1.f + expf(-best));
    float score = sobj * scls;

    float r0 = d[21] + reg_b[0], r1 = d[22] + reg_b[1];
    float r2 = d[23] + reg_b[2], r3 = d[24] + reg_b[3];
    float gx = (float)(pp % WIDTH), gy = (float)(pp / WIDTH);
    float cx = (1.f / (1.f + expf(-r0)) + gx) * 32.f;
    float cy = (1.f / (1.f + expf(-r1)) + gy) * 32.f;
    float bw = expf(r2) * 32.f;
    float bh = expf(r3) * 32.f;
    float hx = 0.5f * bw, hy = 0.5f * bh;

    ((float4*)out)[pp] = make_float4(cx - hx, cy - hy, cx + hx, cy + hy);
    out[HW * 4 + pp] = score;
    out[HW * 5 + pp] = (float)bk;
    out[HW * 6 + pp] = 0.f;

    if (score >= 0.01f) {
        unsigned slot = atomicAdd(&cnt[bk], 1u);
        if (slot < CAP) {
            unsigned sb = __float_as_uint(score) ^ 0xffffffffu;
            keys[bk * CAP + slot] = ((unsigned long long)sb << 32) | (unsigned)pp;
        }
    }
}

// ---------------------------------------------------------------------------
// K2: rank-and-scatter sort. grid = NCLS*16 tiles x 1024 thr, whole-chip.
// Unique keys -> rank == sorted position; O(1) serial depth vs bitonic's
// 55 dependent stages. Lanes >= m substitute 0xFF.. (ws poison guard).
// ---------------------------------------------------------------------------
__global__ __launch_bounds__(1024) void rank_kernel(
    const unsigned* __restrict__ cnt, const unsigned long long* __restrict__ keys,
    unsigned long long* __restrict__ keys2)
{
    __shared__ unsigned long long klds[CAP];
    const int c = blockIdx.x >> 4, tile = blockIdx.x & 15;
    const int tid = threadIdx.x, wave = tid >> 6, lane = tid & 63;
    int m = (int)cnt[c]; if (m > CAP) m = CAP;
    const int rbase = tile << 6;
    if (rbase >= m) return;                      // uniform; before any barrier

    klds[tid] = (tid < m) ? keys[c * CAP + tid] : 0xFFFFFFFFFFFFFFFFull;
    __syncthreads();

#pragma unroll
    for (int rr = 0; rr < 4; ++rr) {
        const int row = rbase + (wave << 2) + rr;         // uniform per wave
        const unsigned long long kr = klds[row];          // broadcast
        int rank = 0;
#pragma unroll
        for (int w = 0; w < 16; ++w) {
            unsigned long long kj = klds[(w << 6) + lane];
            rank += (int)__popcll(__ballot(kj < kr));     // pads never < kr
        }
        if (lane == 0 && row < m)
            keys2[c * CAP + rank] = kr;
    }
}

// ---------------------------------------------------------------------------
// K3a: parallel mask build (verified R3-R8); reads rank-sorted keys2.
// ---------------------------------------------------------------------------
__global__ __launch_bounds__(1024) void build_kernel(
    const unsigned* __restrict__ cnt, const unsigned long long* __restrict__ keys,
    const float* __restrict__ bboxes, unsigned long long* __restrict__ mask)
{
    __shared__ float4 box[CAP];
    const int c = blockIdx.x >> 4, tile = blockIdx.x & 15;
    const int tid = threadIdx.x, wave = tid >> 6, lane = tid & 63;
    int m = (int)cnt[c]; if (m > CAP) m = CAP;
    const int rbase = tile << 6;
    if (rbase >= m) return;                      // uniform; before any barrier

    if (tid < m) {
        unsigned idx = (unsigned)(keys[c * CAP + tid] & 0xffffffffu);
        box[tid] = ((const float4*)bboxes)[idx];
    } else {
        box[tid] = make_float4(0.f, 0.f, 0.f, 0.f);
    }
    __syncthreads();

    unsigned long long* mrow = mask + (size_t)c * CAP * NW;
#pragma unroll 4
    for (int j = 0; j < 64; ++j) {
        const int row = rbase + (wave << 2) + (j >> 4);   // uniform per wave
        const int w   = j & 15;
        const float4 bi = box[row];
        const float4 bj = box[(w << 6) + lane];
        const float ai = (bi.z - bi.x) * (bi.w - bi.y);
        const float aj = (bj.z - bj.x) * (bj.w - bj.y);
        float iw = fminf(bi.z, bj.z) - fmaxf(bi.x, bj.x);
        float ih = fminf(bi.w, bj.w) - fmaxf(bi.y, bj.y);
        iw = fmaxf(iw, 1e-10f);
        ih = fmaxf(ih, 1e-10f);
        const float inter = iw * ih;
        const float iou = inter / (ai + aj - inter);
        unsigned long long word =
            __ballot((row < m) && (((w << 6) + lane) < m) && (iou > 0.5f));
        if (lane == 0) mrow[row * NW + w] = word;
    }
}

// ---------------------------------------------------------------------------
// K3b: greedy sweep, software-pipelined (verified R8); reads keys2.
// ---------------------------------------------------------------------------
__device__ __forceinline__ unsigned long long shflxor64(unsigned long long v, int msk) {
    unsigned lo = __shfl_xor((unsigned)v, msk, 64);
    unsigned hi = __shfl_xor((unsigned)(v >> 32), msk, 64);
    return ((unsigned long long)hi << 32) | lo;
}
__device__ __forceinline__ unsigned long long uread64(unsigned long long v, int srclane) {
    unsigned lo = __builtin_amdgcn_readlane((unsigned)v, srclane);
    unsigned hi = __builtin_amdgcn_readlane((unsigned)(v >> 32), srclane);
    return ((unsigned long long)hi << 32) | lo;
}

__global__ __launch_bounds__(64) void sweep_kernel(
    const unsigned* __restrict__ cnt, const unsigned long long* __restrict__ keys,
    const unsigned long long* __restrict__ mask, float* __restrict__ keep)
{
    const int c = blockIdx.x, lane = threadIdx.x;
    int m = (int)cnt[c]; if (m > CAP) m = CAP;
    const int nw = (m + 63) >> 6;
    if (nw == 0) return;
    const unsigned long long* mrow = mask + (size_t)c * CAP * NW;

    const int wsel = lane & 15;
    const int rof  = lane >> 4;

    // prologue: loads for w = 0
    unsigned long long keyA =
        (lane < m) ? keys[c * CAP + lane] : 0ull;
    unsigned long long rowA =
        (lane < m) ? mrow[(size_t)lane * NW + 0] : 0ull;
    unsigned long long rwA[16];
#pragma unroll
    for (int j = 0; j < 16; ++j) {
        const int r = rof + (j << 2);
        rwA[j] = (r < m && wsel < nw) ? mrow[(size_t)r * NW + wsel] : 0ull;
    }

    unsigned long long remw = 0;     // lane l holds rem word l (l < NW)
    for (int w = 0; w < nw; ++w) {
        const int i0 = w << 6;
        const int nb = min(64, m - i0);

        // stage w+1 (consumed next iteration)
        const bool more = (w + 1 < nw);
        const int  i1   = (w + 1) << 6;
        unsigned long long keyB =
            (more && i1 + lane < m) ? keys[c * CAP + i1 + lane] : 0ull;
        unsigned long long rowB =
            (more && i1 + lane < m) ? mrow[(size_t)(i1 + lane) * NW + (w + 1)] : 0ull;
        unsigned long long rwB[16];
#pragma unroll
        for (int j = 0; j < 16; ++j) {
            const int r = i1 + rof + (j << 2);
            rwB[j] = (more && r < m && wsel < nw)
                         ? mrow[(size_t)r * NW + wsel] : 0ull;
        }

        // serial cascade (verified recurrence)
        unsigned long long cur  = uread64(remw, w);
        unsigned long long kept = 0;
#pragma unroll
        for (int b = 0; b < 64; ++b) {
            unsigned long long x = uread64(rowA, b);
            unsigned long long alive = ((cur >> b) & 1ull) ^ 1ull;
            kept |= alive << b;
            cur |= x & (0ull - alive);
        }
        if (nb < 64) kept &= (1ull << nb) - 1ull;

        if (lane < nb && ((kept >> lane) & 1ull))
            keep[(unsigned)(keyA & 0xffffffffu)] = 1.0f;

        // branch-free OR of kept rows into rem
        unsigned long long part = 0;
#pragma unroll
        for (int j = 0; j < 16; ++j) {
            const int b = rof + (j << 2);
            part |= rwA[j] & (0ull - ((kept >> b) & 1ull));
        }
        part |= shflxor64(part, 16);
        part |= shflxor64(part, 32);
        if (lane < NW) remw |= part;

        // rotate pipeline registers
        keyA = keyB;
        rowA = rowB;
#pragma unroll
        for (int j = 0; j < 16; ++j) rwA[j] = rwB[j];
    }
}

// ---------------------------------------------------------------------------
extern "C" void kernel_launch(void* const* d_in, const int* in_sizes, int n_in,
                              void* d_out, int out_size, void* d_ws, size_t ws_size,
                              hipStream_t stream)
{
    const float* cls_feat = (const float*)d_in[0];
    const float* reg_feat = (const float*)d_in[1];
    const float* obj_w    = (const float*)d_in[2];
    const float* obj_b    = (const float*)d_in[3];
    const float* cls_w    = (const float*)d_in[4];
    const float* cls_b    = (const float*)d_in[5];
    const float* reg_w    = (const float*)d_in[6];
    const float* reg_b    = (const float*)d_in[7];

    float* out = (float*)d_out;
    unsigned* cnt             = (unsigned*)d_ws;
    unsigned long long* keys  = (unsigned long long*)((char*)d_ws + WS_KEYS);
    float* partial            = (float*)((char*)d_ws + WS_PART);
    unsigned long long* mask  = (unsigned long long*)((char*)d_ws + WS_MASK);
    unsigned long long* keys2 = (unsigned long long*)((char*)d_ws + WS_KEY2);

    gemm_stage1<<<288, 256, 0, stream>>>(cls_feat, reg_feat,
                                         obj_w, cls_w, reg_w, partial, cnt);
    decode_stage2<<<HW / 256, 256, 0, stream>>>(partial, obj_b, cls_b, reg_b,
                                                out, cnt, keys);
    rank_kernel<<<NCLS * 16, 1024, 0, stream>>>(cnt, keys, keys2);
    build_kernel<<<NCLS * 16, 1024, 0, stream>>>(cnt, keys2, out, mask);
    sweep_kernel<<<NCLS, 64, 0, stream>>>(cnt, keys2, mask, out + HW * 6);
}